// Round 2
// baseline (518.586 us; speedup 1.0000x reference)
//
#include <hip/hip_runtime.h>

#define NNODES 50000
#define NEDGES 800000
#define BN_EPS 1e-5f
#define NGBLK 782            // ceil(50000 / 64) row-blocks for GEMM
#define NWAVES (NGBLK * 4)   // per-wave stat partial rows

typedef unsigned short u16;
typedef unsigned int u32;
typedef __bf16 bf16x8 __attribute__((ext_vector_type(8)));
typedef float f32x4 __attribute__((ext_vector_type(4)));
typedef float vfloat4 __attribute__((ext_vector_type(4)));
typedef u32 u32x4 __attribute__((ext_vector_type(4)));

__device__ __forceinline__ u16 f2bf(float f) {
    union { float f; u32 u; } v; v.f = f;
    u32 r = v.u + 0x7fffu + ((v.u >> 16) & 1u);   // RNE
    return (u16)(r >> 16);
}
__device__ __forceinline__ float bf2f(u16 s) {
    union { u32 u; float f; } v; v.u = ((u32)s) << 16;
    return v.f;
}

// ---------------- CSR build ----------------

__global__ void k_hist(const int* __restrict__ dst, int* __restrict__ deg) {
    int e = blockIdx.x * 256 + threadIdx.x;   // E divisible by 256
    atomicAdd(&deg[dst[e]], 1);
}

// block scans 1024 elements (256 thr x 4); writes inclusive-scan + block total
__global__ void k_scanA(const int* __restrict__ deg, int* __restrict__ scanned,
                        int* __restrict__ bsum) {
    __shared__ int sd[256];
    int t = threadIdx.x;
    int base = blockIdx.x * 1024 + t * 4;
    int d0 = (base + 0 < NNODES) ? deg[base + 0] : 0;
    int d1 = (base + 1 < NNODES) ? deg[base + 1] : 0;
    int d2 = (base + 2 < NNODES) ? deg[base + 2] : 0;
    int d3 = (base + 3 < NNODES) ? deg[base + 3] : 0;
    int ts = d0 + d1 + d2 + d3;
    sd[t] = ts; __syncthreads();
    for (int off = 1; off < 256; off <<= 1) {
        int v = (t >= off) ? sd[t - off] : 0;
        __syncthreads();
        sd[t] += v;
        __syncthreads();
    }
    int run = sd[t] - ts;   // exclusive prefix of this thread
    run += d0; if (base + 0 < NNODES) scanned[base + 0] = run;
    run += d1; if (base + 1 < NNODES) scanned[base + 1] = run;
    run += d2; if (base + 2 < NNODES) scanned[base + 2] = run;
    run += d3; if (base + 3 < NNODES) scanned[base + 3] = run;
    if (t == 255) bsum[blockIdx.x] = sd[255];
}

__global__ void k_scanB(int* bsum, int nb) {
    if (threadIdx.x == 0) {
        int run = 0;
        for (int i = 0; i < nb; ++i) { int v = bsum[i]; bsum[i] = run; run += v; }
    }
}

__global__ void k_scanC(const int* __restrict__ deg, const int* __restrict__ scanned,
                        const int* __restrict__ bsum, int* __restrict__ row_ptr,
                        int* __restrict__ next_ptr) {
    int i = blockIdx.x * 256 + threadIdx.x;
    if (i < NNODES) {
        int ex = scanned[i] - deg[i] + bsum[i >> 10];
        row_ptr[i] = ex; next_ptr[i] = ex;
        if (i == 0) row_ptr[NNODES] = NEDGES;
    }
}

__global__ void k_scatter(const int* __restrict__ src, const int* __restrict__ dst,
                          int* next_ptr, int* __restrict__ ssorted) {
    int e = blockIdx.x * 256 + threadIdx.x;
    int p = atomicAdd(&next_ptr[dst[e]], 1);
    ssorted[p] = src[e];
}

// ---------------- dtype prep ----------------

// f32 -> bf16, 8 elems/thread (n8 = total/8)
__global__ void k_cvt(const float* __restrict__ in, u16* __restrict__ out, int n8) {
    int i = blockIdx.x * 256 + threadIdx.x;
    if (i >= n8) return;
    const vfloat4* p = (const vfloat4*)(in + (size_t)i * 8);
    vfloat4 a = p[0], b = p[1];
    u32x4 o;
    o[0] = (u32)f2bf(a[0]) | ((u32)f2bf(a[1]) << 16);
    o[1] = (u32)f2bf(a[2]) | ((u32)f2bf(a[3]) << 16);
    o[2] = (u32)f2bf(b[0]) | ((u32)f2bf(b[1]) << 16);
    o[3] = (u32)f2bf(b[2]) | ((u32)f2bf(b[3]) << 16);
    *(u32x4*)(out + (size_t)i * 8) = o;
}

// Pre-shuffle weights into MFMA B-fragment lane order.
// B'[k][o] = k<128 ? Wl[o][k] : Wr[o][k-128];  frag(kk,nt): lane l elem j holds
// B'[kk*32 + (l>>4)*8 + j][nt*16 + (l&15)]
template<int NT>
__global__ void k_prep(const float* __restrict__ Wl, const float* __restrict__ Wr,
                       u16* __restrict__ wfrag) {
    int i = blockIdx.x * 256 + threadIdx.x;   // < 4096*NT
    int j = i & 7, l = (i >> 3) & 63;
    int nt = (i >> 9) & (NT - 1);
    int kk = (i >> 9) / NT;
    int k = kk * 32 + ((l >> 4) << 3) + j;
    int o = nt * 16 + (l & 15);
    float v = (k < 128) ? Wl[o * 128 + k] : Wr[o * 128 + (k - 128)];
    wfrag[i] = f2bf(v);
}

// ---------------- mean aggregation (wave per node, no atomics) ----------------

__global__ __launch_bounds__(256) void k_agg(const int* __restrict__ row_ptr,
                                             const int* __restrict__ ssorted,
                                             const u16* __restrict__ hin,
                                             u16* __restrict__ meanb) {
    int wid = threadIdx.x >> 6, lane = threadIdx.x & 63;
    int node = blockIdx.x * 4 + wid;
    if (node >= NNODES) return;
    int s0 = row_ptr[node], s1 = row_ptr[node + 1];
    float a0 = 0.f, a1 = 0.f;
    for (int e = s0; e < s1; ++e) {
        int s = ssorted[e];
        u32 u = *(const u32*)(hin + (size_t)s * 128 + lane * 2);
        a0 += bf2f((u16)(u & 0xffff));
        a1 += bf2f((u16)(u >> 16));
    }
    int deg = s1 - s0;
    float inv = 1.f / (float)max(deg, 1);
    u32 o = (u32)f2bf(a0 * inv) | ((u32)f2bf(a1 * inv) << 16);
    *(u32*)(meanb + (size_t)node * 128 + lane * 2) = o;
}

// ---------------- fused GEMM: C = [mean|x] @ [Wl;Wr]^T + b (+BN stat partials) --

template<int NT, bool STATS>
__global__ __launch_bounds__(256) void k_gemm(const u16* __restrict__ meanb,
                                              const u16* __restrict__ xb,
                                              const u16* __restrict__ wfrag,
                                              const float* __restrict__ bias,
                                              u16* __restrict__ houtb,
                                              float* __restrict__ outf,
                                              float* __restrict__ ps) {
    int tid = threadIdx.x;
    int wid = tid >> 6, lane = tid & 63;
    int rbase = blockIdx.x * 64 + wid * 16;
    int rA = rbase + (lane & 15);
    if (rA > NNODES - 1) rA = NNODES - 1;   // clamp; masked on store/stats
    int colk = ((lane >> 4) << 3);

    f32x4 acc[NT];
#pragma unroll
    for (int nt = 0; nt < NT; ++nt) { f32x4 z = {0.f, 0.f, 0.f, 0.f}; acc[nt] = z; }

#pragma unroll
    for (int kk = 0; kk < 8; ++kk) {
        const u16* Ab = (kk < 4) ? meanb : xb;
        int c = ((kk & 3) << 5) + colk;
        bf16x8 a = *(const bf16x8*)(Ab + (size_t)rA * 128 + c);
#pragma unroll
        for (int nt = 0; nt < NT; ++nt) {
            bf16x8 b = *(const bf16x8*)(wfrag + ((size_t)((kk * NT + nt) << 6) + lane) * 8);
            acc[nt] = __builtin_amdgcn_mfma_f32_16x16x32_bf16(a, b, acc[nt], 0, 0, 0);
        }
    }

    int wg = blockIdx.x * 4 + wid;
    int colbase = lane & 15;
    int rowoff = ((lane >> 4) << 2);
#pragma unroll
    for (int nt = 0; nt < NT; ++nt) {
        int col = nt * 16 + colbase;
        float bv = bias[col];
        float s1 = 0.f, s2 = 0.f;
#pragma unroll
        for (int ri = 0; ri < 4; ++ri) {
            int row = rbase + rowoff + ri;
            float v = acc[nt][ri] + bv;
            bool ok = row < NNODES;
            if (STATS) {
                float vm = ok ? v : 0.f;
                s1 += vm; s2 += vm * vm;
                // pack 2 cols via lane pair, even lane stores 4B
                float v2 = __shfl_xor(v, 1);
                if (ok && !(lane & 1)) {
                    u32 pk = (u32)f2bf(v) | ((u32)f2bf(v2) << 16);
                    *(u32*)(houtb + (size_t)row * 128 + col) = pk;
                }
            } else {
                if (ok) outf[(size_t)row * (NT * 16) + col] = v;
            }
        }
        if (STATS) {
            s1 += __shfl_down(s1, 32); s1 += __shfl_down(s1, 16);
            s2 += __shfl_down(s2, 32); s2 += __shfl_down(s2, 16);
            if (lane < 16) {
                ps[(size_t)wg * 256 + nt * 16 + lane] = s1;
                ps[(size_t)wg * 256 + 128 + nt * 16 + lane] = s2;
            }
        }
    }
}

// ---------------- BN stat finalize: scale/shift per column ----------------

__global__ void k_bnstat(const float* __restrict__ ps, int nw,
                         const float* __restrict__ gamma, const float* __restrict__ beta,
                         float* __restrict__ scale, float* __restrict__ shift) {
    __shared__ float sd1[256], sd2[256];
    int c = blockIdx.x;   // 0..127
    int t = threadIdx.x;
    float a1 = 0.f, a2 = 0.f;
    for (int w = t; w < nw; w += 256) {
        a1 += ps[(size_t)w * 256 + c];
        a2 += ps[(size_t)w * 256 + 128 + c];
    }
    sd1[t] = a1; sd2[t] = a2; __syncthreads();
    for (int off = 128; off > 0; off >>= 1) {
        if (t < off) { sd1[t] += sd1[t + off]; sd2[t] += sd2[t + off]; }
        __syncthreads();
    }
    if (t == 0) {
        float mu = sd1[0] / (float)NNODES;
        float var = sd2[0] / (float)NNODES - mu * mu;
        float rs = rsqrtf(var + BN_EPS);
        float g = gamma[c];
        scale[c] = rs * g;
        shift[c] = beta[c] - mu * rs * g;
    }
}

// ---------------- BN apply + ReLU (bf16 in -> bf16 out), 8 cols/thread -------

__global__ void k_bnapply(const u16* __restrict__ hb, const float* __restrict__ scale,
                          const float* __restrict__ shift, u16* __restrict__ ob) {
    int i = blockIdx.x * 256 + threadIdx.x;   // < NNODES*16
    if (i >= NNODES * 16) return;
    int c8 = (i & 15) << 3;
    u32x4 u = *(const u32x4*)(hb + (size_t)i * 8);
    u32x4 o;
#pragma unroll
    for (int q = 0; q < 4; ++q) {
        float lo = bf2f((u16)(u[q] & 0xffff)) * scale[c8 + q * 2] + shift[c8 + q * 2];
        float hi = bf2f((u16)(u[q] >> 16)) * scale[c8 + q * 2 + 1] + shift[c8 + q * 2 + 1];
        lo = fmaxf(lo, 0.f); hi = fmaxf(hi, 0.f);
        o[q] = (u32)f2bf(lo) | ((u32)f2bf(hi) << 16);
    }
    *(u32x4*)(ob + (size_t)i * 8) = o;
}

// ---------------- launcher ----------------

extern "C" void kernel_launch(void* const* d_in, const int* in_sizes, int n_in,
                              void* d_out, int out_size, void* d_ws, size_t ws_size,
                              hipStream_t stream) {
    const float* x   = (const float*)d_in[0];
    const int*   ei  = (const int*)d_in[1];
    const float* Wl0 = (const float*)d_in[2];
    const float* bl0 = (const float*)d_in[3];
    const float* Wr0 = (const float*)d_in[4];
    const float* g0  = (const float*)d_in[5];
    const float* be0 = (const float*)d_in[6];
    const float* Wl1 = (const float*)d_in[7];
    const float* bl1 = (const float*)d_in[8];
    const float* Wr1 = (const float*)d_in[9];
    const float* g1  = (const float*)d_in[10];
    const float* be1 = (const float*)d_in[11];
    const float* Wl2 = (const float*)d_in[12];
    const float* bl2 = (const float*)d_in[13];
    const float* Wr2 = (const float*)d_in[14];
    const int* srcp = ei;            // edge_index[0]
    const int* dstp = ei + NEDGES;   // edge_index[1]

    char* w = (char*)d_ws;
    size_t off = 0;
    auto alloc = [&](size_t bytes) -> char* {
        char* p = w + off;
        off += (bytes + 255) & ~(size_t)255;
        return p;
    };
    int* deg      = (int*)alloc(NNODES * 4);
    int* row_ptr  = (int*)alloc((NNODES + 1) * 4);
    int* next_ptr = (int*)alloc(NNODES * 4);
    int* scanned  = (int*)alloc(NNODES * 4);
    int* bsum     = (int*)alloc(64 * 4);
    int* ssorted  = (int*)alloc(NEDGES * 4);
    float* ps     = (float*)alloc((size_t)NWAVES * 256 * 4);
    float* scale  = (float*)alloc(128 * 4);
    float* shift  = (float*)alloc(128 * 4);
    u16* wf0      = (u16*)alloc(32768 * 2);
    u16* wf1      = (u16*)alloc(32768 * 2);
    u16* wf2      = (u16*)alloc(16384 * 2);
    u16* bufA     = (u16*)alloc((size_t)NNODES * 128 * 2);
    u16* bufB     = (u16*)alloc((size_t)NNODES * 128 * 2);
    u16* bufC     = (u16*)alloc((size_t)NNODES * 128 * 2);
    u16* bufD     = (u16*)alloc((size_t)NNODES * 128 * 2);

    // CSR build (reused by all 3 layers)
    hipMemsetAsync(deg, 0, NNODES * 4, stream);
    k_hist<<<NEDGES / 256, 256, 0, stream>>>(dstp, deg);
    k_scanA<<<49, 256, 0, stream>>>(deg, scanned, bsum);
    k_scanB<<<1, 64, 0, stream>>>(bsum, 49);
    k_scanC<<<196, 256, 0, stream>>>(deg, scanned, bsum, row_ptr, next_ptr);
    k_scatter<<<NEDGES / 256, 256, 0, stream>>>(srcp, dstp, next_ptr, ssorted);

    // input + weight prep
    k_cvt<<<3125, 256, 0, stream>>>(x, bufA, NNODES * 16);
    k_prep<8><<<128, 256, 0, stream>>>(Wl0, Wr0, wf0);
    k_prep<8><<<128, 256, 0, stream>>>(Wl1, Wr1, wf1);
    k_prep<4><<<64, 256, 0, stream>>>(Wl2, Wr2, wf2);

    // layer 0: in=bufA -> mean=bufB -> h'=bufC -> bn/relu=bufD
    k_agg<<<12500, 256, 0, stream>>>(row_ptr, ssorted, bufA, bufB);
    k_gemm<8, true><<<NGBLK, 256, 0, stream>>>(bufB, bufA, wf0, bl0, bufC, nullptr, ps);
    k_bnstat<<<128, 256, 0, stream>>>(ps, NWAVES, g0, be0, scale, shift);
    k_bnapply<<<3125, 256, 0, stream>>>(bufC, scale, shift, bufD);

    // layer 1: in=bufD -> mean=bufB -> h'=bufC -> bn/relu=bufA
    k_agg<<<12500, 256, 0, stream>>>(row_ptr, ssorted, bufD, bufB);
    k_gemm<8, true><<<NGBLK, 256, 0, stream>>>(bufB, bufD, wf1, bl1, bufC, nullptr, ps);
    k_bnstat<<<128, 256, 0, stream>>>(ps, NWAVES, g1, be1, scale, shift);
    k_bnapply<<<3125, 256, 0, stream>>>(bufC, scale, shift, bufA);

    // layer 2: in=bufA -> mean=bufB -> out (f32, no BN)
    k_agg<<<12500, 256, 0, stream>>>(row_ptr, ssorted, bufA, bufB);
    k_gemm<4, false><<<NGBLK, 256, 0, stream>>>(bufB, bufA, wf2, bl2, nullptr,
                                                (float*)d_out, ps);
    (void)in_sizes; (void)n_in; (void)out_size; (void)ws_size;
}

// Round 5
// 350.444 us; speedup vs baseline: 1.4798x; 1.4798x over previous
//
#include <hip/hip_runtime.h>

#define NNODES 50000
#define NEDGES 800000
#define BN_EPS 1e-5f
#define NGBLK 782            // ceil(50000 / 64) row-blocks for GEMM
#define NWAVES (NGBLK * 4)   // per-wave stat partial rows

typedef unsigned short u16;
typedef unsigned int u32;
typedef __bf16 bf16x8 __attribute__((ext_vector_type(8)));
typedef float f32x4 __attribute__((ext_vector_type(4)));
typedef float vfloat4 __attribute__((ext_vector_type(4)));
typedef u32 u32x4 __attribute__((ext_vector_type(4)));

__device__ __forceinline__ u16 f2bf(float f) {
    union { float f; u32 u; } v; v.f = f;
    u32 r = v.u + 0x7fffu + ((v.u >> 16) & 1u);   // RNE
    return (u16)(r >> 16);
}
__device__ __forceinline__ float bf2f(u16 s) {
    union { u32 u; float f; } v; v.u = ((u32)s) << 16;
    return v.f;
}

// ---------------- fused prologue: f32->bf16 cvt (blocks 0..3124) + degree hist ----

__global__ void k_pro(const float* __restrict__ x, u16* __restrict__ xb,
                      const int* __restrict__ dst, int* __restrict__ deg) {
    int b = blockIdx.x, t = threadIdx.x;
    if (b < 3125) {                 // NNODES*16 = 800000 = 3125*256 exactly
        int i = b * 256 + t;
        const vfloat4* p = (const vfloat4*)(x + (size_t)i * 8);
        vfloat4 a = p[0], c = p[1];
        u32x4 o;
        o[0] = (u32)f2bf(a[0]) | ((u32)f2bf(a[1]) << 16);
        o[1] = (u32)f2bf(a[2]) | ((u32)f2bf(a[3]) << 16);
        o[2] = (u32)f2bf(c[0]) | ((u32)f2bf(c[1]) << 16);
        o[3] = (u32)f2bf(c[2]) | ((u32)f2bf(c[3]) << 16);
        *(u32x4*)(xb + (size_t)i * 8) = o;
    } else {                        // NEDGES = 800000 = 3125*256 exactly
        int e = (b - 3125) * 256 + t;
        atomicAdd(&deg[dst[e]], 1);
    }
}

// ---------------- CSR build ----------------

// block scans 1024 elements (256 thr x 4); writes inclusive-scan + block total
__global__ void k_scanA(const int* __restrict__ deg, int* __restrict__ scanned,
                        int* __restrict__ bsum) {
    __shared__ int sd[256];
    int t = threadIdx.x;
    int base = blockIdx.x * 1024 + t * 4;
    int d0 = (base + 0 < NNODES) ? deg[base + 0] : 0;
    int d1 = (base + 1 < NNODES) ? deg[base + 1] : 0;
    int d2 = (base + 2 < NNODES) ? deg[base + 2] : 0;
    int d3 = (base + 3 < NNODES) ? deg[base + 3] : 0;
    int ts = d0 + d1 + d2 + d3;
    sd[t] = ts; __syncthreads();
    for (int off = 1; off < 256; off <<= 1) {
        int v = (t >= off) ? sd[t - off] : 0;
        __syncthreads();
        sd[t] += v;
        __syncthreads();
    }
    int run = sd[t] - ts;   // exclusive prefix of this thread
    run += d0; if (base + 0 < NNODES) scanned[base + 0] = run;
    run += d1; if (base + 1 < NNODES) scanned[base + 1] = run;
    run += d2; if (base + 2 < NNODES) scanned[base + 2] = run;
    run += d3; if (base + 3 < NNODES) scanned[base + 3] = run;
    if (t == 255) bsum[blockIdx.x] = sd[255];
}

// per-block inline prefix of the 49 raw block sums (replaces serial scanB kernel)
__global__ void k_scanC(const int* __restrict__ deg, const int* __restrict__ scanned,
                        const int* __restrict__ bsum, int* __restrict__ row_ptr,
                        int* __restrict__ next_ptr) {
    __shared__ int sb0;
    int t = threadIdx.x;
    int nb = blockIdx.x >> 2;   // # of 1024-chunks fully before this block's chunk
    if (t < 64) {
        int v = (t < nb) ? bsum[t] : 0;
        for (int off = 32; off; off >>= 1) v += __shfl_down(v, off);
        if (t == 0) sb0 = v;
    }
    __syncthreads();
    int boff = sb0;
    int i = blockIdx.x * 256 + t;
    if (i < NNODES) {
        int ex = scanned[i] - deg[i] + boff;
        row_ptr[i] = ex; next_ptr[i] = ex;
        if (i == 0) row_ptr[NNODES] = NEDGES;
    }
}

__global__ void k_scatter(const int* __restrict__ src, const int* __restrict__ dst,
                          int* next_ptr, int* __restrict__ ssorted) {
    int e = blockIdx.x * 256 + threadIdx.x;
    int p = atomicAdd(&next_ptr[dst[e]], 1);
    ssorted[p] = src[e];
}

// ---------------- weight prep (all layers in one dispatch) ----------------
// layers 0/1: B'[k][o] = k<128 ? Wl[o][k] : Wr[o][k-128], K=256, NT=8
// layer 2:    two K=128 NT=4 frag sets (Wl2 and Wr2 separately)
// frag(kk,nt): lane l elem j holds B'[kk*32 + (l>>4)*8 + j][nt*16 + (l&15)]

__global__ void k_prepall(const float* __restrict__ Wl0, const float* __restrict__ Wr0,
                          const float* __restrict__ Wl1, const float* __restrict__ Wr1,
                          const float* __restrict__ Wl2, const float* __restrict__ Wr2,
                          u16* __restrict__ wf0, u16* __restrict__ wf1,
                          u16* __restrict__ wf2l, u16* __restrict__ wf2r) {
    int b = blockIdx.x, t = threadIdx.x;
    if (b < 256) {
        const float* Wl = (b < 128) ? Wl0 : Wl1;
        const float* Wr = (b < 128) ? Wr0 : Wr1;
        u16* wf = (b < 128) ? wf0 : wf1;
        int i = (b & 127) * 256 + t;          // < 32768
        int j = i & 7, l = (i >> 3) & 63;
        int nt = (i >> 9) & 7;
        int kk = (i >> 9) >> 3;
        int k = kk * 32 + ((l >> 4) << 3) + j;
        int o = nt * 16 + (l & 15);
        float v = (k < 128) ? Wl[o * 128 + k] : Wr[o * 128 + (k - 128)];
        wf[i] = f2bf(v);
    } else {
        const float* W = (b < 288) ? Wl2 : Wr2;
        u16* wf = (b < 288) ? wf2l : wf2r;
        int i = (b - ((b < 288) ? 256 : 288)) * 256 + t;   // < 8192
        int j = i & 7, l = (i >> 3) & 63;
        int nt = (i >> 9) & 3;
        int kk = (i >> 9) >> 2;
        int k = kk * 32 + ((l >> 4) << 3) + j;
        int o = nt * 16 + (l & 15);
        wf[i] = f2bf(W[o * 128 + k]);
    }
}

// ---------------- mean aggregation, 128-wide rows ----------------
// wave per node; lane = (edge-group eg=lane>>4, feature-chunk fc=lane&15);
// 16B/lane gathers (4 edges per VMEM instr), 2 gathers in flight (8 edges/iter);
// edge indices prefetched 64-at-a-time and broadcast via shfl.

#define ADD8(u) do { \
    acc[0] += bf2f((u16)((u)[0] & 0xffff)); acc[1] += bf2f((u16)((u)[0] >> 16)); \
    acc[2] += bf2f((u16)((u)[1] & 0xffff)); acc[3] += bf2f((u16)((u)[1] >> 16)); \
    acc[4] += bf2f((u16)((u)[2] & 0xffff)); acc[5] += bf2f((u16)((u)[2] >> 16)); \
    acc[6] += bf2f((u16)((u)[3] & 0xffff)); acc[7] += bf2f((u16)((u)[3] >> 16)); } while (0)

__global__ __launch_bounds__(256) void k_agg128(const int* __restrict__ row_ptr,
                                                const int* __restrict__ ssorted,
                                                const u16* __restrict__ hin,
                                                u16* __restrict__ meanb) {
    int wid = threadIdx.x >> 6, lane = threadIdx.x & 63;
    int node = blockIdx.x * 4 + wid;
    if (node >= NNODES) return;
    int s0 = row_ptr[node], s1 = row_ptr[node + 1];
    int eg = lane >> 4, fc = lane & 15;
    float acc[8] = {0.f, 0.f, 0.f, 0.f, 0.f, 0.f, 0.f, 0.f};

    for (int base = s0; base < s1; base += 64) {
        int cnt = min(64, s1 - base);
        int idxv = (lane < cnt) ? ssorted[base + lane] : 0;
        int full = cnt & ~7;
        int e = 0;
        for (; e < full; e += 8) {
            int i0 = __shfl(idxv, e + eg);
            int i1 = __shfl(idxv, e + 4 + eg);
            u32x4 u0 = *(const u32x4*)(hin + (size_t)i0 * 128 + fc * 8);
            u32x4 u1 = *(const u32x4*)(hin + (size_t)i1 * 128 + fc * 8);
            ADD8(u0); ADD8(u1);
        }
        if (e < cnt) {
            int sl0 = e + eg, sl1 = e + 4 + eg;
            int i0 = __shfl(idxv, sl0 < cnt ? sl0 : 0);
            int i1 = __shfl(idxv, sl1 < cnt ? sl1 : 0);
            if (sl0 < cnt) { u32x4 u0 = *(const u32x4*)(hin + (size_t)i0 * 128 + fc * 8); ADD8(u0); }
            if (sl1 < cnt) { u32x4 u1 = *(const u32x4*)(hin + (size_t)i1 * 128 + fc * 8); ADD8(u1); }
        }
    }
#pragma unroll
    for (int j = 0; j < 8; ++j) {
        acc[j] += __shfl_xor(acc[j], 16);
        acc[j] += __shfl_xor(acc[j], 32);
    }
    int deg = s1 - s0;
    float inv = 1.f / (float)max(deg, 1);
    if (eg == 0) {
        u32x4 o;
#pragma unroll
        for (int q = 0; q < 4; ++q)
            o[q] = (u32)f2bf(acc[2 * q] * inv) | ((u32)f2bf(acc[2 * q + 1] * inv) << 16);
        *(u32x4*)(meanb + (size_t)node * 128 + fc * 8) = o;
    }
}

// ---------------- mean aggregation, 64-wide rows (layer 2, z domain) ----------
// gathers z rows (128B), accumulates mean*inv into d_out (RMW, self-term already there)

__global__ __launch_bounds__(256) void k_agg64(const int* __restrict__ row_ptr,
                                               const int* __restrict__ ssorted,
                                               const u16* __restrict__ zb,
                                               float* __restrict__ outf) {
    int wid = threadIdx.x >> 6, lane = threadIdx.x & 63;
    int node = blockIdx.x * 4 + wid;
    if (node >= NNODES) return;
    int s0 = row_ptr[node], s1 = row_ptr[node + 1];
    int eg = lane >> 3, fc = lane & 7;
    float acc[8] = {0.f, 0.f, 0.f, 0.f, 0.f, 0.f, 0.f, 0.f};

    for (int base = s0; base < s1; base += 64) {
        int cnt = min(64, s1 - base);
        int idxv = (lane < cnt) ? ssorted[base + lane] : 0;
        int full = cnt & ~15;
        int e = 0;
        for (; e < full; e += 16) {
            int i0 = __shfl(idxv, e + eg);
            int i1 = __shfl(idxv, e + 8 + eg);
            u32x4 u0 = *(const u32x4*)(zb + (size_t)i0 * 64 + fc * 8);
            u32x4 u1 = *(const u32x4*)(zb + (size_t)i1 * 64 + fc * 8);
            ADD8(u0); ADD8(u1);
        }
        if (e < cnt) {
            int sl0 = e + eg, sl1 = e + 8 + eg;
            int i0 = __shfl(idxv, sl0 < cnt ? sl0 : 0);
            int i1 = __shfl(idxv, sl1 < cnt ? sl1 : 0);
            if (sl0 < cnt) { u32x4 u0 = *(const u32x4*)(zb + (size_t)i0 * 64 + fc * 8); ADD8(u0); }
            if (sl1 < cnt) { u32x4 u1 = *(const u32x4*)(zb + (size_t)i1 * 64 + fc * 8); ADD8(u1); }
        }
    }
#pragma unroll
    for (int j = 0; j < 8; ++j) {
        acc[j] += __shfl_xor(acc[j], 8);
        acc[j] += __shfl_xor(acc[j], 16);
        acc[j] += __shfl_xor(acc[j], 32);
    }
    int deg = s1 - s0;
    float inv = 1.f / (float)max(deg, 1);
    if (eg == 0) {
        vfloat4* p = (vfloat4*)(outf + (size_t)node * 64 + fc * 8);
        vfloat4 a = p[0], b = p[1];
        a[0] += acc[0] * inv; a[1] += acc[1] * inv; a[2] += acc[2] * inv; a[3] += acc[3] * inv;
        b[0] += acc[4] * inv; b[1] += acc[5] * inv; b[2] += acc[6] * inv; b[3] += acc[7] * inv;
        p[0] = a; p[1] = b;
    }
}

// ---------------- fused GEMM: C = [mean|x] @ [Wl;Wr]^T + b (+BN stat partials) --

template<int NT, bool STATS>
__global__ __launch_bounds__(256) void k_gemm(const u16* __restrict__ meanb,
                                              const u16* __restrict__ xb,
                                              const u16* __restrict__ wfrag,
                                              const float* __restrict__ bias,
                                              u16* __restrict__ houtb,
                                              float* __restrict__ outf,
                                              float* __restrict__ ps) {
    int tid = threadIdx.x;
    int wid = tid >> 6, lane = tid & 63;
    int rbase = blockIdx.x * 64 + wid * 16;
    int rA = rbase + (lane & 15);
    if (rA > NNODES - 1) rA = NNODES - 1;   // clamp; masked on store/stats
    int colk = ((lane >> 4) << 3);

    f32x4 acc[NT];
#pragma unroll
    for (int nt = 0; nt < NT; ++nt) { f32x4 z = {0.f, 0.f, 0.f, 0.f}; acc[nt] = z; }

#pragma unroll
    for (int kk = 0; kk < 8; ++kk) {
        const u16* Ab = (kk < 4) ? meanb : xb;
        int c = ((kk & 3) << 5) + colk;
        bf16x8 a = *(const bf16x8*)(Ab + (size_t)rA * 128 + c);
#pragma unroll
        for (int nt = 0; nt < NT; ++nt) {
            bf16x8 b = *(const bf16x8*)(wfrag + ((size_t)((kk * NT + nt) << 6) + lane) * 8);
            acc[nt] = __builtin_amdgcn_mfma_f32_16x16x32_bf16(a, b, acc[nt], 0, 0, 0);
        }
    }

    int wg = blockIdx.x * 4 + wid;
    int colbase = lane & 15;
    int rowoff = ((lane >> 4) << 2);
#pragma unroll
    for (int nt = 0; nt < NT; ++nt) {
        int col = nt * 16 + colbase;
        float bv = bias[col];
        float s1 = 0.f, s2 = 0.f;
#pragma unroll
        for (int ri = 0; ri < 4; ++ri) {
            int row = rbase + rowoff + ri;
            float v = acc[nt][ri] + bv;
            bool ok = row < NNODES;
            if (STATS) {
                float vm = ok ? v : 0.f;
                s1 += vm; s2 += vm * vm;
                // pack 2 cols via lane pair, even lane stores 4B
                float v2 = __shfl_xor(v, 1);
                if (ok && !(lane & 1)) {
                    u32 pk = (u32)f2bf(v) | ((u32)f2bf(v2) << 16);
                    *(u32*)(houtb + (size_t)row * 128 + col) = pk;
                }
            } else {
                if (ok) outf[(size_t)row * (NT * 16) + col] = v;
            }
        }
        if (STATS) {
            s1 += __shfl_down(s1, 32); s1 += __shfl_down(s1, 16);
            s2 += __shfl_down(s2, 32); s2 += __shfl_down(s2, 16);
            if (lane < 16) {
                ps[(size_t)wg * 256 + nt * 16 + lane] = s1;
                ps[(size_t)wg * 256 + 128 + nt * 16 + lane] = s2;
            }
        }
    }
}

// ---------------- layer-2 GEMM: z = h@Wl2^T (bf16), self = h@Wr2^T + b (f32->out)

__global__ __launch_bounds__(256) void k_gemm2(const u16* __restrict__ hb,
                                               const u16* __restrict__ wfl,
                                               const u16* __restrict__ wfr,
                                               const float* __restrict__ bias,
                                               u16* __restrict__ zb,
                                               float* __restrict__ outf) {
    int tid = threadIdx.x;
    int wid = tid >> 6, lane = tid & 63;
    int rbase = blockIdx.x * 64 + wid * 16;
    int rA = rbase + (lane & 15);
    if (rA > NNODES - 1) rA = NNODES - 1;
    int colk = ((lane >> 4) << 3);

    f32x4 az[4], as[4];
#pragma unroll
    for (int nt = 0; nt < 4; ++nt) { f32x4 z = {0.f, 0.f, 0.f, 0.f}; az[nt] = z; as[nt] = z; }

#pragma unroll
    for (int kk = 0; kk < 4; ++kk) {
        int c = (kk << 5) + colk;
        bf16x8 a = *(const bf16x8*)(hb + (size_t)rA * 128 + c);
#pragma unroll
        for (int nt = 0; nt < 4; ++nt) {
            bf16x8 bl = *(const bf16x8*)(wfl + ((size_t)((kk * 4 + nt) << 6) + lane) * 8);
            bf16x8 br = *(const bf16x8*)(wfr + ((size_t)((kk * 4 + nt) << 6) + lane) * 8);
            az[nt] = __builtin_amdgcn_mfma_f32_16x16x32_bf16(a, bl, az[nt], 0, 0, 0);
            as[nt] = __builtin_amdgcn_mfma_f32_16x16x32_bf16(a, br, as[nt], 0, 0, 0);
        }
    }

    int colbase = lane & 15;
    int rowoff = ((lane >> 4) << 2);
#pragma unroll
    for (int nt = 0; nt < 4; ++nt) {
        int col = nt * 16 + colbase;
        float bv = bias[col];
#pragma unroll
        for (int ri = 0; ri < 4; ++ri) {
            int row = rbase + rowoff + ri;
            bool ok = row < NNODES;
            float zv = az[nt][ri];
            float z2 = __shfl_xor(zv, 1);
            if (ok && !(lane & 1)) {
                u32 pk = (u32)f2bf(zv) | ((u32)f2bf(z2) << 16);
                *(u32*)(zb + (size_t)row * 64 + col) = pk;
            }
            if (ok) outf[(size_t)row * 64 + col] = as[nt][ri] + bv;
        }
    }
}

// ---------------- BN stat finalize: scale/shift per column ----------------

__global__ void k_bnstat(const float* __restrict__ ps, int nw,
                         const float* __restrict__ gamma, const float* __restrict__ beta,
                         float* __restrict__ scale, float* __restrict__ shift) {
    __shared__ float sd1[256], sd2[256];
    int c = blockIdx.x;   // 0..127
    int t = threadIdx.x;
    float a1 = 0.f, a2 = 0.f;
    for (int w = t; w < nw; w += 256) {
        a1 += ps[(size_t)w * 256 + c];
        a2 += ps[(size_t)w * 256 + 128 + c];
    }
    sd1[t] = a1; sd2[t] = a2; __syncthreads();
    for (int off = 128; off > 0; off >>= 1) {
        if (t < off) { sd1[t] += sd1[t + off]; sd2[t] += sd2[t + off]; }
        __syncthreads();
    }
    if (t == 0) {
        float mu = sd1[0] / (float)NNODES;
        float var = sd2[0] / (float)NNODES - mu * mu;
        float rs = rsqrtf(var + BN_EPS);
        float g = gamma[c];
        scale[c] = rs * g;
        shift[c] = beta[c] - mu * rs * g;
    }
}

// ---------------- BN apply + ReLU (bf16 in -> bf16 out), 8 cols/thread -------

__global__ void k_bnapply(const u16* __restrict__ hb, const float* __restrict__ scale,
                          const float* __restrict__ shift, u16* __restrict__ ob) {
    int i = blockIdx.x * 256 + threadIdx.x;   // < NNODES*16
    if (i >= NNODES * 16) return;
    int c8 = (i & 15) << 3;
    u32x4 u = *(const u32x4*)(hb + (size_t)i * 8);
    u32x4 o;
#pragma unroll
    for (int q = 0; q < 4; ++q) {
        float lo = bf2f((u16)(u[q] & 0xffff)) * scale[c8 + q * 2] + shift[c8 + q * 2];
        float hi = bf2f((u16)(u[q] >> 16)) * scale[c8 + q * 2 + 1] + shift[c8 + q * 2 + 1];
        lo = fmaxf(lo, 0.f); hi = fmaxf(hi, 0.f);
        o[q] = (u32)f2bf(lo) | ((u32)f2bf(hi) << 16);
    }
    *(u32x4*)(ob + (size_t)i * 8) = o;
}

// ---------------- launcher ----------------

extern "C" void kernel_launch(void* const* d_in, const int* in_sizes, int n_in,
                              void* d_out, int out_size, void* d_ws, size_t ws_size,
                              hipStream_t stream) {
    const float* x   = (const float*)d_in[0];
    const int*   ei  = (const int*)d_in[1];
    const float* Wl0 = (const float*)d_in[2];
    const float* bl0 = (const float*)d_in[3];
    const float* Wr0 = (const float*)d_in[4];
    const float* g0  = (const float*)d_in[5];
    const float* be0 = (const float*)d_in[6];
    const float* Wl1 = (const float*)d_in[7];
    const float* bl1 = (const float*)d_in[8];
    const float* Wr1 = (const float*)d_in[9];
    const float* g1  = (const float*)d_in[10];
    const float* be1 = (const float*)d_in[11];
    const float* Wl2 = (const float*)d_in[12];
    const float* bl2 = (const float*)d_in[13];
    const float* Wr2 = (const float*)d_in[14];
    const int* srcp = ei;            // edge_index[0]
    const int* dstp = ei + NEDGES;   // edge_index[1]

    char* w = (char*)d_ws;
    size_t off = 0;
    auto alloc = [&](size_t bytes) -> char* {
        char* p = w + off;
        off += (bytes + 255) & ~(size_t)255;
        return p;
    };
    int* deg      = (int*)alloc(NNODES * 4);
    int* row_ptr  = (int*)alloc((NNODES + 1) * 4);
    int* next_ptr = (int*)alloc(NNODES * 4);
    int* scanned  = (int*)alloc(NNODES * 4);
    int* bsum     = (int*)alloc(64 * 4);
    int* ssorted  = (int*)alloc(NEDGES * 4);
    float* ps     = (float*)alloc((size_t)NWAVES * 256 * 4);
    float* scale  = (float*)alloc(128 * 4);
    float* shift  = (float*)alloc(128 * 4);
    u16* wf0      = (u16*)alloc(32768 * 2);
    u16* wf1      = (u16*)alloc(32768 * 2);
    u16* wf2l     = (u16*)alloc(8192 * 2);
    u16* wf2r     = (u16*)alloc(8192 * 2);
    u16* bufA     = (u16*)alloc((size_t)NNODES * 128 * 2);
    u16* bufB     = (u16*)alloc((size_t)NNODES * 128 * 2);
    u16* bufC     = (u16*)alloc((size_t)NNODES * 128 * 2);
    u16* bufD     = (u16*)alloc((size_t)NNODES * 128 * 2);
    u16* zb       = (u16*)alloc((size_t)NNODES * 64 * 2);

    // prologue: cvt + degree histogram, then CSR build, then weight prep
    hipMemsetAsync(deg, 0, NNODES * 4, stream);
    k_pro<<<6250, 256, 0, stream>>>(x, bufA, dstp, deg);
    k_scanA<<<49, 256, 0, stream>>>(deg, scanned, bsum);
    k_scanC<<<196, 256, 0, stream>>>(deg, scanned, bsum, row_ptr, next_ptr);
    k_scatter<<<3125, 256, 0, stream>>>(srcp, dstp, next_ptr, ssorted);
    k_prepall<<<320, 256, 0, stream>>>(Wl0, Wr0, Wl1, Wr1, Wl2, Wr2,
                                       wf0, wf1, wf2l, wf2r);

    // layer 0: in=bufA -> mean=bufB -> h'=bufC -> bn/relu=bufD
    k_agg128<<<12500, 256, 0, stream>>>(row_ptr, ssorted, bufA, bufB);
    k_gemm<8, true><<<NGBLK, 256, 0, stream>>>(bufB, bufA, wf0, bl0, bufC, nullptr, ps);
    k_bnstat<<<128, 256, 0, stream>>>(ps, NWAVES, g0, be0, scale, shift);
    k_bnapply<<<3125, 256, 0, stream>>>(bufC, scale, shift, bufD);

    // layer 1: in=bufD -> mean=bufB -> h'=bufC -> bn/relu=bufA
    k_agg128<<<12500, 256, 0, stream>>>(row_ptr, ssorted, bufD, bufB);
    k_gemm<8, true><<<NGBLK, 256, 0, stream>>>(bufB, bufD, wf1, bl1, bufC, nullptr, ps);
    k_bnstat<<<128, 256, 0, stream>>>(ps, NWAVES, g1, be1, scale, shift);
    k_bnapply<<<3125, 256, 0, stream>>>(bufC, scale, shift, bufA);

    // layer 2 (matmul-before-aggregate): z = h@Wl2^T, out = h@Wr2^T + b, then out += mean(z)
    k_gemm2<<<NGBLK, 256, 0, stream>>>(bufA, wf2l, wf2r, bl2, zb, (float*)d_out);
    k_agg64<<<12500, 256, 0, stream>>>(row_ptr, ssorted, zb, (float*)d_out);

    (void)in_sizes; (void)n_in; (void)out_size; (void)ws_size;
}

// Round 6
// 317.791 us; speedup vs baseline: 1.6318x; 1.1028x over previous
//
#include <hip/hip_runtime.h>

#define NNODES 50000
#define NEDGES 800000
#define BN_EPS 1e-5f
#define NGBLK 782            // ceil(50000 / 64) row-blocks for GEMM
#define NWAVES (NGBLK * 4)   // per-wave stat partial rows
#define NCOPY 8              // privatized histogram copies

typedef unsigned short u16;
typedef unsigned int u32;
typedef __bf16 bf16x8 __attribute__((ext_vector_type(8)));
typedef float f32x4 __attribute__((ext_vector_type(4)));
typedef float vfloat4 __attribute__((ext_vector_type(4)));
typedef u32 u32x4 __attribute__((ext_vector_type(4)));

__device__ __forceinline__ u16 f2bf(float f) {
    union { float f; u32 u; } v; v.f = f;
    u32 r = v.u + 0x7fffu + ((v.u >> 16) & 1u);   // RNE
    return (u16)(r >> 16);
}
__device__ __forceinline__ float bf2f(u16 s) {
    union { u32 u; float f; } v; v.u = ((u32)s) << 16;
    return v.f;
}

// ------- fused prologue: f32->bf16 cvt (blocks 0..3124) + privatized hist + rank ----
// hist copy c = (edge_block & 7); rank[e] = position within (c, dst) bucket.

__global__ void k_pro(const float* __restrict__ x, u16* __restrict__ xb,
                      const int* __restrict__ dst, int* __restrict__ deg8,
                      u16* __restrict__ rank) {
    int b = blockIdx.x, t = threadIdx.x;
    if (b < 3125) {                 // NNODES*16 = 800000 = 3125*256 exactly
        int i = b * 256 + t;
        const vfloat4* p = (const vfloat4*)(x + (size_t)i * 8);
        vfloat4 a = p[0], c = p[1];
        u32x4 o;
        o[0] = (u32)f2bf(a[0]) | ((u32)f2bf(a[1]) << 16);
        o[1] = (u32)f2bf(a[2]) | ((u32)f2bf(a[3]) << 16);
        o[2] = (u32)f2bf(c[0]) | ((u32)f2bf(c[1]) << 16);
        o[3] = (u32)f2bf(c[2]) | ((u32)f2bf(c[3]) << 16);
        *(u32x4*)(xb + (size_t)i * 8) = o;
    } else {                        // NEDGES = 800000 = 3125*256 exactly
        int eb = b - 3125;
        int e = eb * 256 + t;
        int c = eb & (NCOPY - 1);
        rank[e] = (u16)atomicAdd(&deg8[c * NNODES + dst[e]], 1);
    }
}

// ---------------- CSR build ----------------

// block scans 1024 node-degrees (sum over 8 copies); inclusive scan + block total
__global__ void k_scanA(const int* __restrict__ deg8, int* __restrict__ scanned,
                        int* __restrict__ bsum) {
    __shared__ int sd[256];
    int t = threadIdx.x;
    int base = blockIdx.x * 1024 + t * 4;
    int d0 = 0, d1 = 0, d2 = 0, d3 = 0;
#pragma unroll
    for (int c = 0; c < NCOPY; ++c) {
        const int* dc = deg8 + c * NNODES;
        if (base + 0 < NNODES) d0 += dc[base + 0];
        if (base + 1 < NNODES) d1 += dc[base + 1];
        if (base + 2 < NNODES) d2 += dc[base + 2];
        if (base + 3 < NNODES) d3 += dc[base + 3];
    }
    int ts = d0 + d1 + d2 + d3;
    sd[t] = ts; __syncthreads();
    for (int off = 1; off < 256; off <<= 1) {
        int v = (t >= off) ? sd[t - off] : 0;
        __syncthreads();
        sd[t] += v;
        __syncthreads();
    }
    int run = sd[t] - ts;   // exclusive prefix of this thread
    run += d0; if (base + 0 < NNODES) scanned[base + 0] = run;
    run += d1; if (base + 1 < NNODES) scanned[base + 1] = run;
    run += d2; if (base + 2 < NNODES) scanned[base + 2] = run;
    run += d3; if (base + 3 < NNODES) scanned[base + 3] = run;
    if (t == 255) bsum[blockIdx.x] = sd[255];
}

// row_ptr + per-copy bases; inline prefix of the 49 block sums
__global__ void k_scanC(const int* __restrict__ deg8, const int* __restrict__ scanned,
                        const int* __restrict__ bsum, int* __restrict__ row_ptr,
                        int* __restrict__ base8) {
    __shared__ int sb0;
    int t = threadIdx.x;
    int nb = blockIdx.x >> 2;   // # of 1024-chunks fully before this block's chunk
    if (t < 64) {
        int v = (t < nb) ? bsum[t] : 0;
        for (int off = 32; off; off >>= 1) v += __shfl_down(v, off);
        if (t == 0) sb0 = v;
    }
    __syncthreads();
    int boff = sb0;
    int i = blockIdx.x * 256 + t;
    if (i < NNODES) {
        int d[NCOPY];
        int dtot = 0;
#pragma unroll
        for (int c = 0; c < NCOPY; ++c) { d[c] = deg8[c * NNODES + i]; dtot += d[c]; }
        int ex = scanned[i] - dtot + boff;
        row_ptr[i] = ex;
        int run = ex;
#pragma unroll
        for (int c = 0; c < NCOPY; ++c) { base8[c * NNODES + i] = run; run += d[c]; }
        if (i == 0) row_ptr[NNODES] = NEDGES;
    }
}

// atomic-free scatter: position = base8[copy][dst] + rank
__global__ void k_scatter(const int* __restrict__ src, const int* __restrict__ dst,
                          const int* __restrict__ base8, const u16* __restrict__ rank,
                          int* __restrict__ ssorted) {
    int e = blockIdx.x * 256 + threadIdx.x;
    int c = (e >> 8) & (NCOPY - 1);   // matches k_pro's eb & 7
    int p = base8[c * NNODES + dst[e]] + (int)rank[e];
    ssorted[p] = src[e];
}

// ---------------- weight prep (all layers in one dispatch) ----------------
// layers 0/1: B'[k][o] = k<128 ? Wl[o][k] : Wr[o][k-128], K=256, NT=8
// layer 2:    two K=128 NT=4 frag sets (Wl2 and Wr2 separately)
// frag(kk,nt): lane l elem j holds B'[kk*32 + (l>>4)*8 + j][nt*16 + (l&15)]

__global__ void k_prepall(const float* __restrict__ Wl0, const float* __restrict__ Wr0,
                          const float* __restrict__ Wl1, const float* __restrict__ Wr1,
                          const float* __restrict__ Wl2, const float* __restrict__ Wr2,
                          u16* __restrict__ wf0, u16* __restrict__ wf1,
                          u16* __restrict__ wf2l, u16* __restrict__ wf2r) {
    int b = blockIdx.x, t = threadIdx.x;
    if (b < 256) {
        const float* Wl = (b < 128) ? Wl0 : Wl1;
        const float* Wr = (b < 128) ? Wr0 : Wr1;
        u16* wf = (b < 128) ? wf0 : wf1;
        int i = (b & 127) * 256 + t;          // < 32768
        int j = i & 7, l = (i >> 3) & 63;
        int nt = (i >> 9) & 7;
        int kk = (i >> 9) >> 3;
        int k = kk * 32 + ((l >> 4) << 3) + j;
        int o = nt * 16 + (l & 15);
        float v = (k < 128) ? Wl[o * 128 + k] : Wr[o * 128 + (k - 128)];
        wf[i] = f2bf(v);
    } else {
        const float* W = (b < 288) ? Wl2 : Wr2;
        u16* wf = (b < 288) ? wf2l : wf2r;
        int i = (b - ((b < 288) ? 256 : 288)) * 256 + t;   // < 8192
        int j = i & 7, l = (i >> 3) & 63;
        int nt = (i >> 9) & 3;
        int kk = (i >> 9) >> 2;
        int k = kk * 32 + ((l >> 4) << 3) + j;
        int o = nt * 16 + (l & 15);
        wf[i] = f2bf(W[o * 128 + k]);
    }
}

// ---------------- mean aggregation, 128-wide rows ----------------
// wave per node; lane = (edge-group eg=lane>>4, feature-chunk fc=lane&15);
// 16B/lane gathers (4 edges per VMEM instr), 2 gathers in flight (8 edges/iter);
// edge indices prefetched 64-at-a-time and broadcast via shfl.

#define ADD8(u) do { \
    acc[0] += bf2f((u16)((u)[0] & 0xffff)); acc[1] += bf2f((u16)((u)[0] >> 16)); \
    acc[2] += bf2f((u16)((u)[1] & 0xffff)); acc[3] += bf2f((u16)((u)[1] >> 16)); \
    acc[4] += bf2f((u16)((u)[2] & 0xffff)); acc[5] += bf2f((u16)((u)[2] >> 16)); \
    acc[6] += bf2f((u16)((u)[3] & 0xffff)); acc[7] += bf2f((u16)((u)[3] >> 16)); } while (0)

__global__ __launch_bounds__(256) void k_agg128(const int* __restrict__ row_ptr,
                                                const int* __restrict__ ssorted,
                                                const u16* __restrict__ hin,
                                                u16* __restrict__ meanb) {
    int wid = threadIdx.x >> 6, lane = threadIdx.x & 63;
    int node = blockIdx.x * 4 + wid;
    if (node >= NNODES) return;
    int s0 = row_ptr[node], s1 = row_ptr[node + 1];
    int eg = lane >> 4, fc = lane & 15;
    float acc[8] = {0.f, 0.f, 0.f, 0.f, 0.f, 0.f, 0.f, 0.f};

    for (int base = s0; base < s1; base += 64) {
        int cnt = min(64, s1 - base);
        int idxv = (lane < cnt) ? ssorted[base + lane] : 0;
        int full = cnt & ~7;
        int e = 0;
        for (; e < full; e += 8) {
            int i0 = __shfl(idxv, e + eg);
            int i1 = __shfl(idxv, e + 4 + eg);
            u32x4 u0 = *(const u32x4*)(hin + (size_t)i0 * 128 + fc * 8);
            u32x4 u1 = *(const u32x4*)(hin + (size_t)i1 * 128 + fc * 8);
            ADD8(u0); ADD8(u1);
        }
        if (e < cnt) {
            int sl0 = e + eg, sl1 = e + 4 + eg;
            int i0 = __shfl(idxv, sl0 < cnt ? sl0 : 0);
            int i1 = __shfl(idxv, sl1 < cnt ? sl1 : 0);
            if (sl0 < cnt) { u32x4 u0 = *(const u32x4*)(hin + (size_t)i0 * 128 + fc * 8); ADD8(u0); }
            if (sl1 < cnt) { u32x4 u1 = *(const u32x4*)(hin + (size_t)i1 * 128 + fc * 8); ADD8(u1); }
        }
    }
#pragma unroll
    for (int j = 0; j < 8; ++j) {
        acc[j] += __shfl_xor(acc[j], 16);
        acc[j] += __shfl_xor(acc[j], 32);
    }
    int deg = s1 - s0;
    float inv = 1.f / (float)max(deg, 1);
    if (eg == 0) {
        u32x4 o;
#pragma unroll
        for (int q = 0; q < 4; ++q)
            o[q] = (u32)f2bf(acc[2 * q] * inv) | ((u32)f2bf(acc[2 * q + 1] * inv) << 16);
        *(u32x4*)(meanb + (size_t)node * 128 + fc * 8) = o;
    }
}

// ---------------- mean aggregation, 64-wide rows (layer 2, z domain) ----------
// gathers z rows (128B), accumulates mean*inv into d_out (RMW, self-term already there)

__global__ __launch_bounds__(256) void k_agg64(const int* __restrict__ row_ptr,
                                               const int* __restrict__ ssorted,
                                               const u16* __restrict__ zb,
                                               float* __restrict__ outf) {
    int wid = threadIdx.x >> 6, lane = threadIdx.x & 63;
    int node = blockIdx.x * 4 + wid;
    if (node >= NNODES) return;
    int s0 = row_ptr[node], s1 = row_ptr[node + 1];
    int eg = lane >> 3, fc = lane & 7;
    float acc[8] = {0.f, 0.f, 0.f, 0.f, 0.f, 0.f, 0.f, 0.f};

    for (int base = s0; base < s1; base += 64) {
        int cnt = min(64, s1 - base);
        int idxv = (lane < cnt) ? ssorted[base + lane] : 0;
        int full = cnt & ~15;
        int e = 0;
        for (; e < full; e += 16) {
            int i0 = __shfl(idxv, e + eg);
            int i1 = __shfl(idxv, e + 8 + eg);
            u32x4 u0 = *(const u32x4*)(zb + (size_t)i0 * 64 + fc * 8);
            u32x4 u1 = *(const u32x4*)(zb + (size_t)i1 * 64 + fc * 8);
            ADD8(u0); ADD8(u1);
        }
        if (e < cnt) {
            int sl0 = e + eg, sl1 = e + 8 + eg;
            int i0 = __shfl(idxv, sl0 < cnt ? sl0 : 0);
            int i1 = __shfl(idxv, sl1 < cnt ? sl1 : 0);
            if (sl0 < cnt) { u32x4 u0 = *(const u32x4*)(zb + (size_t)i0 * 64 + fc * 8); ADD8(u0); }
            if (sl1 < cnt) { u32x4 u1 = *(const u32x4*)(zb + (size_t)i1 * 64 + fc * 8); ADD8(u1); }
        }
    }
#pragma unroll
    for (int j = 0; j < 8; ++j) {
        acc[j] += __shfl_xor(acc[j], 8);
        acc[j] += __shfl_xor(acc[j], 16);
        acc[j] += __shfl_xor(acc[j], 32);
    }
    int deg = s1 - s0;
    float inv = 1.f / (float)max(deg, 1);
    if (eg == 0) {
        vfloat4* p = (vfloat4*)(outf + (size_t)node * 64 + fc * 8);
        vfloat4 a = p[0], b = p[1];
        a[0] += acc[0] * inv; a[1] += acc[1] * inv; a[2] += acc[2] * inv; a[3] += acc[3] * inv;
        b[0] += acc[4] * inv; b[1] += acc[5] * inv; b[2] += acc[6] * inv; b[3] += acc[7] * inv;
        p[0] = a; p[1] = b;
    }
}

// ---------------- fused GEMM: C = [mean|x] @ [Wl;Wr]^T + b (+BN stat partials) --

template<int NT, bool STATS>
__global__ __launch_bounds__(256) void k_gemm(const u16* __restrict__ meanb,
                                              const u16* __restrict__ xb,
                                              const u16* __restrict__ wfrag,
                                              const float* __restrict__ bias,
                                              u16* __restrict__ houtb,
                                              float* __restrict__ outf,
                                              float* __restrict__ ps) {
    int tid = threadIdx.x;
    int wid = tid >> 6, lane = tid & 63;
    int rbase = blockIdx.x * 64 + wid * 16;
    int rA = rbase + (lane & 15);
    if (rA > NNODES - 1) rA = NNODES - 1;   // clamp; masked on store/stats
    int colk = ((lane >> 4) << 3);

    f32x4 acc[NT];
#pragma unroll
    for (int nt = 0; nt < NT; ++nt) { f32x4 z = {0.f, 0.f, 0.f, 0.f}; acc[nt] = z; }

#pragma unroll
    for (int kk = 0; kk < 8; ++kk) {
        const u16* Ab = (kk < 4) ? meanb : xb;
        int c = ((kk & 3) << 5) + colk;
        bf16x8 a = *(const bf16x8*)(Ab + (size_t)rA * 128 + c);
#pragma unroll
        for (int nt = 0; nt < NT; ++nt) {
            bf16x8 b = *(const bf16x8*)(wfrag + ((size_t)((kk * NT + nt) << 6) + lane) * 8);
            acc[nt] = __builtin_amdgcn_mfma_f32_16x16x32_bf16(a, b, acc[nt], 0, 0, 0);
        }
    }

    int wg = blockIdx.x * 4 + wid;
    int colbase = lane & 15;
    int rowoff = ((lane >> 4) << 2);
#pragma unroll
    for (int nt = 0; nt < NT; ++nt) {
        int col = nt * 16 + colbase;
        float bv = bias[col];
        float s1 = 0.f, s2 = 0.f;
#pragma unroll
        for (int ri = 0; ri < 4; ++ri) {
            int row = rbase + rowoff + ri;
            float v = acc[nt][ri] + bv;
            bool ok = row < NNODES;
            if (STATS) {
                float vm = ok ? v : 0.f;
                s1 += vm; s2 += vm * vm;
                // pack 2 cols via lane pair, even lane stores 4B
                float v2 = __shfl_xor(v, 1);
                if (ok && !(lane & 1)) {
                    u32 pk = (u32)f2bf(v) | ((u32)f2bf(v2) << 16);
                    *(u32*)(houtb + (size_t)row * 128 + col) = pk;
                }
            } else {
                if (ok) outf[(size_t)row * (NT * 16) + col] = v;
            }
        }
        if (STATS) {
            s1 += __shfl_down(s1, 32); s1 += __shfl_down(s1, 16);
            s2 += __shfl_down(s2, 32); s2 += __shfl_down(s2, 16);
            if (lane < 16) {
                ps[(size_t)wg * 256 + nt * 16 + lane] = s1;
                ps[(size_t)wg * 256 + 128 + nt * 16 + lane] = s2;
            }
        }
    }
}

// ---------------- layer-2 GEMM: z = h@Wl2^T (bf16), self = h@Wr2^T + b (f32->out)

__global__ __launch_bounds__(256) void k_gemm2(const u16* __restrict__ hb,
                                               const u16* __restrict__ wfl,
                                               const u16* __restrict__ wfr,
                                               const float* __restrict__ bias,
                                               u16* __restrict__ zb,
                                               float* __restrict__ outf) {
    int tid = threadIdx.x;
    int wid = tid >> 6, lane = tid & 63;
    int rbase = blockIdx.x * 64 + wid * 16;
    int rA = rbase + (lane & 15);
    if (rA > NNODES - 1) rA = NNODES - 1;
    int colk = ((lane >> 4) << 3);

    f32x4 az[4], as[4];
#pragma unroll
    for (int nt = 0; nt < 4; ++nt) { f32x4 z = {0.f, 0.f, 0.f, 0.f}; az[nt] = z; as[nt] = z; }

#pragma unroll
    for (int kk = 0; kk < 4; ++kk) {
        int c = (kk << 5) + colk;
        bf16x8 a = *(const bf16x8*)(hb + (size_t)rA * 128 + c);
#pragma unroll
        for (int nt = 0; nt < 4; ++nt) {
            bf16x8 bl = *(const bf16x8*)(wfl + ((size_t)((kk * 4 + nt) << 6) + lane) * 8);
            bf16x8 br = *(const bf16x8*)(wfr + ((size_t)((kk * 4 + nt) << 6) + lane) * 8);
            az[nt] = __builtin_amdgcn_mfma_f32_16x16x32_bf16(a, bl, az[nt], 0, 0, 0);
            as[nt] = __builtin_amdgcn_mfma_f32_16x16x32_bf16(a, br, as[nt], 0, 0, 0);
        }
    }

    int colbase = lane & 15;
    int rowoff = ((lane >> 4) << 2);
#pragma unroll
    for (int nt = 0; nt < 4; ++nt) {
        int col = nt * 16 + colbase;
        float bv = bias[col];
#pragma unroll
        for (int ri = 0; ri < 4; ++ri) {
            int row = rbase + rowoff + ri;
            bool ok = row < NNODES;
            float zv = az[nt][ri];
            float z2 = __shfl_xor(zv, 1);
            if (ok && !(lane & 1)) {
                u32 pk = (u32)f2bf(zv) | ((u32)f2bf(z2) << 16);
                *(u32*)(zb + (size_t)row * 64 + col) = pk;
            }
            if (ok) outf[(size_t)row * 64 + col] = as[nt][ri] + bv;
        }
    }
}

// ---------------- BN stat finalize: scale/shift per column ----------------

__global__ void k_bnstat(const float* __restrict__ ps, int nw,
                         const float* __restrict__ gamma, const float* __restrict__ beta,
                         float* __restrict__ scale, float* __restrict__ shift) {
    __shared__ float sd1[256], sd2[256];
    int c = blockIdx.x;   // 0..127
    int t = threadIdx.x;
    float a1 = 0.f, a2 = 0.f;
    for (int w = t; w < nw; w += 256) {
        a1 += ps[(size_t)w * 256 + c];
        a2 += ps[(size_t)w * 256 + 128 + c];
    }
    sd1[t] = a1; sd2[t] = a2; __syncthreads();
    for (int off = 128; off > 0; off >>= 1) {
        if (t < off) { sd1[t] += sd1[t + off]; sd2[t] += sd2[t + off]; }
        __syncthreads();
    }
    if (t == 0) {
        float mu = sd1[0] / (float)NNODES;
        float var = sd2[0] / (float)NNODES - mu * mu;
        float rs = rsqrtf(var + BN_EPS);
        float g = gamma[c];
        scale[c] = rs * g;
        shift[c] = beta[c] - mu * rs * g;
    }
}

// ---------------- BN apply + ReLU (bf16 in -> bf16 out), 8 cols/thread -------

__global__ void k_bnapply(const u16* __restrict__ hb, const float* __restrict__ scale,
                          const float* __restrict__ shift, u16* __restrict__ ob) {
    int i = blockIdx.x * 256 + threadIdx.x;   // < NNODES*16
    if (i >= NNODES * 16) return;
    int c8 = (i & 15) << 3;
    u32x4 u = *(const u32x4*)(hb + (size_t)i * 8);
    u32x4 o;
#pragma unroll
    for (int q = 0; q < 4; ++q) {
        float lo = bf2f((u16)(u[q] & 0xffff)) * scale[c8 + q * 2] + shift[c8 + q * 2];
        float hi = bf2f((u16)(u[q] >> 16)) * scale[c8 + q * 2 + 1] + shift[c8 + q * 2 + 1];
        lo = fmaxf(lo, 0.f); hi = fmaxf(hi, 0.f);
        o[q] = (u32)f2bf(lo) | ((u32)f2bf(hi) << 16);
    }
    *(u32x4*)(ob + (size_t)i * 8) = o;
}

// ---------------- launcher ----------------

extern "C" void kernel_launch(void* const* d_in, const int* in_sizes, int n_in,
                              void* d_out, int out_size, void* d_ws, size_t ws_size,
                              hipStream_t stream) {
    const float* x   = (const float*)d_in[0];
    const int*   ei  = (const int*)d_in[1];
    const float* Wl0 = (const float*)d_in[2];
    const float* bl0 = (const float*)d_in[3];
    const float* Wr0 = (const float*)d_in[4];
    const float* g0  = (const float*)d_in[5];
    const float* be0 = (const float*)d_in[6];
    const float* Wl1 = (const float*)d_in[7];
    const float* bl1 = (const float*)d_in[8];
    const float* Wr1 = (const float*)d_in[9];
    const float* g1  = (const float*)d_in[10];
    const float* be1 = (const float*)d_in[11];
    const float* Wl2 = (const float*)d_in[12];
    const float* bl2 = (const float*)d_in[13];
    const float* Wr2 = (const float*)d_in[14];
    const int* srcp = ei;            // edge_index[0]
    const int* dstp = ei + NEDGES;   // edge_index[1]

    char* w = (char*)d_ws;
    size_t off = 0;
    auto alloc = [&](size_t bytes) -> char* {
        char* p = w + off;
        off += (bytes + 255) & ~(size_t)255;
        return p;
    };
    int* deg8     = (int*)alloc((size_t)NCOPY * NNODES * 4);
    int* base8    = (int*)alloc((size_t)NCOPY * NNODES * 4);
    u16* rank     = (u16*)alloc((size_t)NEDGES * 2);
    int* row_ptr  = (int*)alloc((NNODES + 1) * 4);
    int* scanned  = (int*)alloc(NNODES * 4);
    int* bsum     = (int*)alloc(64 * 4);
    int* ssorted  = (int*)alloc(NEDGES * 4);
    float* ps     = (float*)alloc((size_t)NWAVES * 256 * 4);
    float* scale  = (float*)alloc(128 * 4);
    float* shift  = (float*)alloc(128 * 4);
    u16* wf0      = (u16*)alloc(32768 * 2);
    u16* wf1      = (u16*)alloc(32768 * 2);
    u16* wf2l     = (u16*)alloc(8192 * 2);
    u16* wf2r     = (u16*)alloc(8192 * 2);
    u16* bufA     = (u16*)alloc((size_t)NNODES * 128 * 2);
    u16* bufB     = (u16*)alloc((size_t)NNODES * 128 * 2);
    u16* bufC     = (u16*)alloc((size_t)NNODES * 128 * 2);
    u16* bufD     = (u16*)alloc((size_t)NNODES * 128 * 2);
    u16* zb       = (u16*)alloc((size_t)NNODES * 64 * 2);

    // prologue: cvt + privatized degree hist (+rank), then CSR build, weight prep
    hipMemsetAsync(deg8, 0, (size_t)NCOPY * NNODES * 4, stream);
    k_pro<<<6250, 256, 0, stream>>>(x, bufA, dstp, deg8, rank);
    k_scanA<<<49, 256, 0, stream>>>(deg8, scanned, bsum);
    k_scanC<<<196, 256, 0, stream>>>(deg8, scanned, bsum, row_ptr, base8);
    k_scatter<<<3125, 256, 0, stream>>>(srcp, dstp, base8, rank, ssorted);
    k_prepall<<<320, 256, 0, stream>>>(Wl0, Wr0, Wl1, Wr1, Wl2, Wr2,
                                       wf0, wf1, wf2l, wf2r);

    // layer 0: in=bufA -> mean=bufB -> h'=bufC -> bn/relu=bufD
    k_agg128<<<12500, 256, 0, stream>>>(row_ptr, ssorted, bufA, bufB);
    k_gemm<8, true><<<NGBLK, 256, 0, stream>>>(bufB, bufA, wf0, bl0, bufC, nullptr, ps);
    k_bnstat<<<128, 256, 0, stream>>>(ps, NWAVES, g0, be0, scale, shift);
    k_bnapply<<<3125, 256, 0, stream>>>(bufC, scale, shift, bufD);

    // layer 1: in=bufD -> mean=bufB -> h'=bufC -> bn/relu=bufA
    k_agg128<<<12500, 256, 0, stream>>>(row_ptr, ssorted, bufD, bufB);
    k_gemm<8, true><<<NGBLK, 256, 0, stream>>>(bufB, bufD, wf1, bl1, bufC, nullptr, ps);
    k_bnstat<<<128, 256, 0, stream>>>(ps, NWAVES, g1, be1, scale, shift);
    k_bnapply<<<3125, 256, 0, stream>>>(bufC, scale, shift, bufA);

    // layer 2 (matmul-before-aggregate): z = h@Wl2^T, out = h@Wr2^T + b, then out += mean(z)
    k_gemm2<<<NGBLK, 256, 0, stream>>>(bufA, wf2l, wf2r, bl2, zb, (float*)d_out);
    k_agg64<<<12500, 256, 0, stream>>>(row_ptr, ssorted, zb, (float*)d_out);

    (void)in_sizes; (void)n_in; (void)out_size; (void)ws_size;
}